// Round 7
// baseline (1464.463 us; speedup 1.0000x reference)
//
#include <hip/hip_runtime.h>
#include <cstdint>
#include <cstddef>

typedef unsigned short u16;
typedef __bf16 bf16x8 __attribute__((ext_vector_type(8)));
typedef float f32x4 __attribute__((ext_vector_type(4)));

constexpr int Bz = 8, Sq = 512, Hh = 8, DKd = 64, Dm = 512, Dff = 2048, NL = 4;
constexpr int TOK = Bz * Sq;               // 4096 tokens
constexpr size_t MAT = (size_t)512 * 512;  // 262144 elems per 512x512 matrix
constexpr size_t EL  = (size_t)TOK * Dm;   // 2097152 elems per activation tensor
constexpr size_t WFT = (size_t)Dff * Dm;   // 1048576 elems per FFN matrix

__device__ __forceinline__ float bf2f(u16 u) {
  union { uint32_t i; float f; } v; v.i = (uint32_t)u << 16; return v.f;
}
__device__ __forceinline__ u16 f2bf(float f) {
  union { float f; uint32_t i; } v; v.f = f;
  uint32_t i = v.i;
  i += 0x7fffu + ((i >> 16) & 1u);   // round-to-nearest-even
  return (u16)(i >> 16);
}

// async global -> LDS, 16B per lane (global_load_lds_dwordx4)
__device__ __forceinline__ void gload16(const u16* g, u16* l) {
  __builtin_amdgcn_global_load_lds(
      (const __attribute__((address_space(1))) unsigned int*)g,
      (__attribute__((address_space(3))) unsigned int*)l, 16, 0, 0);
}

// ---------------------------------------------------------------------------
// Tiled NT GEMM: C[M,N] = A[M,K] @ Bt[N,K]^T (+bias fp32) (+relu)
// 256 threads = 4 waves (2x2); BK=64; global_load_lds staging, XOR chunk
// swizzle (c ^= row&7) -> ~2-way bank-safe ds_read_b128.
// cmode 0: plain write; 4: qkv split (Q scaled 0.125, Q->C [B,H,S,DK],
//          K->C+EL [B,H,S,DK], V->C+2EL transposed [B,H,DK,S]).
// A2/xsplit: blocks with blockIdx.x >= xsplit read A2 and write cols 512+.
// ---------------------------------------------------------------------------
template<int BM, int BN>
__global__ __launch_bounds__(256)
void gemm_tile(const u16* __restrict__ A, const u16* __restrict__ Bt,
               const float* __restrict__ bias, u16* __restrict__ C,
               int K, int lda, long long sA, int ldb, long long sB,
               int ldc, long long sC, int cmode, int relu, int colofs,
               const u16* A2, int xsplit)
{
  constexpr int HM = BM / 2, HN = BN / 2, MI = HM / 16, NI = HN / 16;
  __shared__ __align__(16) u16 As[BM * 64];
  __shared__ __align__(16) u16 Bs[BN * 64];
  const int bz = blockIdx.z;
  const u16* Abase = A;
  int colbase;
  if (A2 && (int)blockIdx.x >= xsplit) {
    Abase = A2;
    colbase = 512 + ((int)blockIdx.x - xsplit) * BN;
  } else {
    colbase = colofs + (int)blockIdx.x * BN;
  }
  const u16* Ab = Abase + (size_t)bz * (size_t)sA + (size_t)(blockIdx.y * BM) * lda;
  const u16* Bb = Bt + (size_t)bz * (size_t)sB + (size_t)colbase * ldb;
  const int tid  = threadIdx.x;
  const int lane = tid & 63;
  const int wid  = tid >> 6;
  const int l15  = lane & 15;
  const int quad = lane >> 4;
  const int wm   = wid >> 1, wn = wid & 1;

  f32x4 acc[MI][NI] = {};

  for (int k0 = 0; k0 < K; k0 += 64) {
#pragma unroll
    for (int i = 0; i < BM / 32; ++i) {          // A: BM rows x 64, 8 chunks/row
      const int s = tid + i * 256;
      const int row = s >> 3, c = (s & 7) ^ (row & 7);
      gload16(Ab + (size_t)row * lda + k0 + c * 8, As + s * 8);
    }
#pragma unroll
    for (int i = 0; i < BN / 32; ++i) {
      const int s = tid + i * 256;
      const int row = s >> 3, c = (s & 7) ^ (row & 7);
      gload16(Bb + (size_t)row * ldb + k0 + c * 8, Bs + s * 8);
    }
    __syncthreads();
#pragma unroll
    for (int kk = 0; kk < 2; ++kk) {
      bf16x8 af[MI], bfr[NI];
#pragma unroll
      for (int mi = 0; mi < MI; ++mi) {
        const int ra = wm * HM + mi * 16 + l15;
        af[mi] = *(const bf16x8*)(As + ra * 64 + (((kk * 4 + quad) ^ (ra & 7))) * 8);
      }
#pragma unroll
      for (int ni = 0; ni < NI; ++ni) {
        const int rb = wn * HN + ni * 16 + l15;
        bfr[ni] = *(const bf16x8*)(Bs + rb * 64 + (((kk * 4 + quad) ^ (rb & 7))) * 8);
      }
#pragma unroll
      for (int mi = 0; mi < MI; ++mi)
#pragma unroll
        for (int ni = 0; ni < NI; ++ni)
          acc[mi][ni] = __builtin_amdgcn_mfma_f32_16x16x32_bf16(af[mi], bfr[ni], acc[mi][ni], 0, 0, 0);
    }
    __syncthreads();
  }

  const int rblk = blockIdx.y * BM + wm * HM + quad * 4;
#pragma unroll
  for (int ni = 0; ni < NI; ++ni) {
    const int colx = colbase + wn * HN + ni * 16 + l15;
    const float bv = bias ? bias[colx] : 0.f;
#pragma unroll
    for (int mi = 0; mi < MI; ++mi) {
#pragma unroll
      for (int r = 0; r < 4; ++r) {
        float v = acc[mi][ni][r] + bv;
        if (relu) v = fmaxf(v, 0.f);
        const int grow = rblk + mi * 16 + r;
        size_t off;
        if (cmode == 0) {
          off = (size_t)bz * (size_t)sC + (size_t)grow * ldc + colx;
        } else {  // 4: qkv scatter; fold 1/sqrt(DK)=0.125 into Q
          const int sec = colx >> 9, n = colx & 511, h = n >> 6, d = n & 63;
          const int b = grow >> 9, s = grow & 511;
          if (sec == 0) v *= 0.125f;
          if (sec < 2) off = (size_t)sec * EL + (size_t)b * 262144 + (size_t)h * 32768 + (size_t)s * 64 + d;
          else         off = 2 * EL + (size_t)b * 262144 + (size_t)h * 32768 + (size_t)d * 512 + s;
        }
        C[off] = f2bf(v);
      }
    }
  }
}

// ---------------------------------------------------------------------------
// Fused attention: per block = (q-tile of 64 rows, one (b,h)).
// ctx[b,s,h*64+d] = softmax(mask(Q K^T)) V.  Q pre-scaled by 0.125.
// mtype 1 (causal): chunks beyond the q-tile's diagonal are fully masked ->
// skipped entirely (bit-exact: their P is identically 0).
// ---------------------------------------------------------------------------
__global__ __launch_bounds__(256)
void flash_attn(const u16* __restrict__ q, const u16* __restrict__ k,
                const u16* __restrict__ v, const unsigned char* __restrict__ pad,
                u16* __restrict__ ctx, int mtype)
{
  __shared__ __align__(16) u16 KVs[8192];      // 16 KB: K or V chunk (swizzled)
  __shared__ __align__(16) u16 Pw[4][2048];    // 4 KB per wave: P tile 16x128
  const int bh = blockIdx.y, b = bh >> 3, h = bh & 7;
  const int qt = blockIdx.x;
  const int tid = threadIdx.x, lane = tid & 63, wid = tid >> 6;
  const int l15 = lane & 15, quad = lane >> 4;
  const size_t bho = (size_t)bh * 32768;
  const int qrow = qt * 64 + wid * 16 + l15;       // A-operand row (this lane)
  const int qcd  = qt * 64 + wid * 16 + quad * 4;  // C-layout row base
  const int nkc  = (mtype == 1) ? (qt >> 1) + 1 : 4;  // live key chunks (uniform)

  unsigned char* Ps = (unsigned char*)&Pw[0][0];
  if (tid < 128) ((uchar4*)Ps)[tid] = ((const uchar4*)(pad + b * 512))[tid];

  bf16x8 aq0 = *(const bf16x8*)(q + bho + (size_t)qrow * 64 + quad * 8);
  bf16x8 aq1 = *(const bf16x8*)(q + bho + (size_t)qrow * 64 + 32 + quad * 8);

  f32x4 S[32];
#pragma unroll
  for (int kc = 0; kc < 4; ++kc) {
    if (kc < nkc) {
      __syncthreads();
#pragma unroll
      for (int i = 0; i < 4; ++i) {             // stage K chunk [128 keys][64]
        const int s = tid + i * 256;
        const int row = s >> 3, c = (s & 7) ^ (row & 7);
        gload16(k + bho + (size_t)(kc * 128 + row) * 64 + c * 8, KVs + s * 8);
      }
      __syncthreads();
#pragma unroll
      for (int t = 0; t < 8; ++t) {
        const int sw = l15 & 7;
        bf16x8 b0 = *(const bf16x8*)(KVs + (t * 16 + l15) * 64 + (quad ^ sw) * 8);
        bf16x8 b1 = *(const bf16x8*)(KVs + (t * 16 + l15) * 64 + ((4 + quad) ^ sw) * 8);
        f32x4 z = {0.f, 0.f, 0.f, 0.f};
        z = __builtin_amdgcn_mfma_f32_16x16x32_bf16(aq0, b0, z, 0, 0, 0);
        S[kc * 8 + t] = __builtin_amdgcn_mfma_f32_16x16x32_bf16(aq1, b1, z, 0, 0, 0);
      }
    }
  }

  unsigned pm = 0u;
#pragma unroll
  for (int t = 0; t < 32; ++t) pm |= (unsigned)(Ps[t * 16 + l15] != 0) << t;

  float inv[4];
#pragma unroll
  for (int r = 0; r < 4; ++r) {
    const int qg = qcd + r;
    float mx = -3.0e38f;
#pragma unroll
    for (int t = 0; t < 32; ++t) {
      if (t < nkc * 8) {
        const int col = t * 16 + l15;
        const bool m = ((pm >> t) & 1u) || (mtype == 1 && col > qg);
        const float val = m ? -1e9f : S[t][r];
        S[t][r] = val;
        mx = fmaxf(mx, val);
      }
    }
#pragma unroll
    for (int o = 8; o > 0; o >>= 1) mx = fmaxf(mx, __shfl_xor(mx, o));
    float sm = 0.f;
#pragma unroll
    for (int t = 0; t < 32; ++t) {
      if (t < nkc * 8) { const float e = __expf(S[t][r] - mx); S[t][r] = e; sm += e; }
    }
#pragma unroll
    for (int o = 8; o > 0; o >>= 1) sm += __shfl_xor(sm, o);
    inv[r] = 1.f / sm;
  }

  f32x4 O[4] = {};
  u16* myP = &Pw[wid][0];
#pragma unroll
  for (int kc = 0; kc < 4; ++kc) {
    if (kc < nkc) {
      __syncthreads();
#pragma unroll
      for (int i = 0; i < 4; ++i) {             // stage V chunk [64 dk][128 keys]
        const int s = tid + i * 256;
        const int row = s >> 4, c = (s & 15) ^ (row & 15);
        gload16(v + bho + (size_t)row * 512 + kc * 128 + c * 8, KVs + s * 8);
      }
#pragma unroll
      for (int t = 0; t < 8; ++t)
#pragma unroll
        for (int r = 0; r < 4; ++r) {
          const int rowq = quad * 4 + r;
          const int c = 2 * t + (l15 >> 3);
          myP[rowq * 128 + (c ^ rowq) * 8 + (l15 & 7)] = f2bf(S[kc * 8 + t][r] * inv[r]);
        }
      __syncthreads();
#pragma unroll
      for (int kk = 0; kk < 4; ++kk) {
        bf16x8 ap = *(const bf16x8*)(myP + l15 * 128 + ((kk * 4 + quad) ^ l15) * 8);
#pragma unroll
        for (int ni = 0; ni < 4; ++ni) {
          bf16x8 bv = *(const bf16x8*)(KVs + (ni * 16 + l15) * 128 + ((kk * 4 + quad) ^ l15) * 8);
          O[ni] = __builtin_amdgcn_mfma_f32_16x16x32_bf16(ap, bv, O[ni], 0, 0, 0);
        }
      }
    }
  }

  const int token = b * 512 + qcd;
#pragma unroll
  for (int ni = 0; ni < 4; ++ni)
#pragma unroll
    for (int r = 0; r < 4; ++r)
      ctx[(size_t)(token + r) * 512 + h * 64 + ni * 16 + l15] = f2bf(O[ni][r]);
}

// all 48 weight transposes in one dispatch (fp32 [K,N] -> bf16 [N,K])
__global__ __launch_bounds__(256)
void transpose_all(const float* __restrict__ s0, const float* __restrict__ s1,
                   const float* __restrict__ s2, const float* __restrict__ s3,
                   const float* __restrict__ s4, const float* __restrict__ s5,
                   u16* __restrict__ out)
{
  __shared__ float tile[32][33];
  const int z = blockIdx.z;
  const float* src; int zi;
  if      (z < 12) { src = s0; zi = z; }
  else if (z < 24) { src = s1; zi = z - 12; }
  else if (z < 36) { src = s2; zi = z - 24; }
  else if (z < 40) { src = s3; zi = z - 36; }
  else if (z < 44) { src = s4; zi = z - 40; }
  else             { src = s5; zi = z - 44; }
  const float* in = src + (size_t)zi * MAT;
  u16* o = out + (size_t)z * MAT;
  int x = blockIdx.x * 32 + threadIdx.x;
  int y = blockIdx.y * 32 + threadIdx.y;
#pragma unroll
  for (int i = 0; i < 32; i += 8)
    tile[threadIdx.y + i][threadIdx.x] = in[(size_t)(y + i) * 512 + x];
  __syncthreads();
  x = blockIdx.y * 32 + threadIdx.x;
  y = blockIdx.x * 32 + threadIdx.y;
#pragma unroll
  for (int i = 0; i < 32; i += 8)
    o[(size_t)(y + i) * 512 + x] = f2bf(tile[threadIdx.x][threadIdx.y + i]);
}

// convert 4 fp32 tensors (n elems each) -> bf16, packed consecutively in out
__global__ __launch_bounds__(256)
void convert4(const float* __restrict__ a, const float* __restrict__ b,
              const float* __restrict__ c, const float* __restrict__ d,
              u16* __restrict__ out, int n)
{
  const float* srcs[4] = { a, b, c, d };
  const float* src = srcs[blockIdx.y];
  u16* dst = out + (size_t)blockIdx.y * n;
  int i = (blockIdx.x * 256 + threadIdx.x) * 4;
  if (i < n) {
    float4 v = *(const float4*)(src + i);
    ushort4 u = { f2bf(v.x), f2bf(v.y), f2bf(v.z), f2bf(v.w) };
    *(ushort4*)(dst + i) = u;
  }
}

// embed both enc and dec (blockIdx.y selects): out = concat(x, x@ew^T+eb)+pos,
// written as bf16 (GEMM input) AND fp32 (residual shadow); also pad flags.
__global__ __launch_bounds__(256)
void embed_k(const float* __restrict__ xe, const float* __restrict__ xd,
             const float* __restrict__ ew, const float* __restrict__ eb,
             const float* __restrict__ pos,
             u16* __restrict__ oe, u16* __restrict__ od,
             float* __restrict__ oeF, float* __restrict__ odF,
             unsigned char* __restrict__ pe, unsigned char* __restrict__ pd)
{
  const int which = blockIdx.y;
  const float* x = which ? xd : xe;
  u16* out = which ? od : oe;
  float* outF = which ? odF : oeF;
  unsigned char* padv = which ? pd : pe;
  const int rs = blockIdx.x;          // b*512 + s
  const int s  = rs & 511;
  __shared__ float xr[32];
  const int t = threadIdx.x;
  if (t < 32) xr[t] = x[(size_t)rs * 32 + t];
  __syncthreads();
  if (t == 0) {
    float sacc = 0.f;
#pragma unroll
    for (int f = 0; f < 32; ++f) sacc += xr[f];
    padv[rs] = (sacc <= -9999.f) ? 1 : 0;
  }
#pragma unroll
  for (int rep = 0; rep < 2; ++rep) {
    const int c = t + rep * 256;
    float v;
    if (c < 32) {
      v = xr[c];
    } else {
      const float* w = ew + (size_t)(c - 32) * 32;
      float acc = eb[c - 32];
#pragma unroll
      for (int f = 0; f < 32; ++f) acc += xr[f] * w[f];
      v = acc;
    }
    v += pos[(size_t)(s + 1) * 512 + c];
    out[(size_t)rs * 512 + c] = f2bf(v);
    outF[(size_t)rs * 512 + c] = v;
  }
}

// wave-per-row LN(xresF + y), torch-style (ddof=1, /(std+eps)). 4 rows/block.
// Residual kept in fp32 (xresF, updated in place); bf16 copy written for GEMMs.
__global__ __launch_bounds__(256)
void add_ln(float* __restrict__ xresF, const u16* __restrict__ y,
            const float* __restrict__ g, const float* __restrict__ bb,
            u16* __restrict__ xout)
{
  const int row  = blockIdx.x * 4 + (threadIdx.x >> 6);
  const int lane = threadIdx.x & 63;
  const int c0 = lane * 8;
  const size_t base = (size_t)row * Dm + c0;

  float4 x0 = *(const float4*)(xresF + base);
  float4 x1 = *(const float4*)(xresF + base + 4);
  uint4 yr = *(const uint4*)(y + base);
  const u16* yh = (const u16*)&yr;
  float z[8] = { x0.x, x0.y, x0.z, x0.w, x1.x, x1.y, x1.z, x1.w };
  float s = 0.f;
#pragma unroll
  for (int j = 0; j < 8; ++j) { z[j] += bf2f(yh[j]); s += z[j]; }
#pragma unroll
  for (int off = 32; off > 0; off >>= 1) s += __shfl_xor(s, off);
  const float mean = s * (1.f / 512.f);
  float ss = 0.f;
#pragma unroll
  for (int j = 0; j < 8; ++j) { z[j] -= mean; ss += z[j] * z[j]; }
#pragma unroll
  for (int off = 32; off > 0; off >>= 1) ss += __shfl_xor(ss, off);
  const float stdv = sqrtf(ss * (1.f / 511.f));
  const float inv = 1.f / (stdv + 1e-6f);

  float4 g0 = *(const float4*)(g + c0),  g1 = *(const float4*)(g + c0 + 4);
  float4 b0 = *(const float4*)(bb + c0), b1 = *(const float4*)(bb + c0 + 4);
  float gv[8] = { g0.x, g0.y, g0.z, g0.w, g1.x, g1.y, g1.z, g1.w };
  float bv[8] = { b0.x, b0.y, b0.z, b0.w, b1.x, b1.y, b1.z, b1.w };
  float o[8];
  uint4 ow;
  u16* oh = (u16*)&ow;
#pragma unroll
  for (int j = 0; j < 8; ++j) { o[j] = gv[j] * z[j] * inv + bv[j]; oh[j] = f2bf(o[j]); }
  *(uint4*)(xout + base) = ow;
  float4 f0 = { o[0], o[1], o[2], o[3] }, f1 = { o[4], o[5], o[6], o[7] };
  *(float4*)(xresF + base) = f0;
  *(float4*)(xresF + base + 4) = f1;
}

extern "C" void kernel_launch(void* const* d_in, const int* in_sizes, int n_in,
                              void* d_out, int out_size, void* d_ws, size_t ws_size,
                              hipStream_t stream)
{
  (void)in_sizes; (void)n_in; (void)out_size;
  const float* enc_in   = (const float*)d_in[0];
  const float* dec_in   = (const float*)d_in[1];
  const float* emb_w    = (const float*)d_in[2];
  const float* emb_b    = (const float*)d_in[3];
  const float* pos      = (const float*)d_in[4];
  const float* e_qkv_b  = (const float*)d_in[6];
  const float* e_pb     = (const float*)d_in[8];
  const float* e_ln1    = (const float*)d_in[9];
  const float* e_b1     = (const float*)d_in[11];
  const float* e_b2     = (const float*)d_in[13];
  const float* e_ln2    = (const float*)d_in[14];
  const float* ds_qkv_b = (const float*)d_in[16];
  const float* ds_pb    = (const float*)d_in[18];
  const float* d_ln1    = (const float*)d_in[19];
  const float* dc_qkv_b = (const float*)d_in[21];
  const float* dc_pb    = (const float*)d_in[23];
  const float* d_ln2    = (const float*)d_in[24];
  const float* d_b1     = (const float*)d_in[26];
  const float* d_b2     = (const float*)d_in[28];
  const float* d_ln3    = (const float*)d_in[29];
  const float* e_qkv_w  = (const float*)d_in[5];
  const float* e_pw     = (const float*)d_in[7];
  const float* e_w1     = (const float*)d_in[10];
  const float* e_w2     = (const float*)d_in[12];
  const float* ds_qkv_w = (const float*)d_in[15];
  const float* ds_pw    = (const float*)d_in[17];
  const float* dc_qkv_w = (const float*)d_in[20];
  const float* dc_pw    = (const float*)d_in[22];
  const float* d_w1     = (const float*)d_in[25];
  const float* d_w2     = (const float*)d_in[27];

  u16* ws  = (u16*)d_ws;
  u16* enc = ws;             // EL
  u16* dec = ws + EL;        // EL
  u16* qb  = ws + 2 * EL;    // EL [B,H,S,DK]  (K at +EL, V^T at +2EL)
  u16* kb  = ws + 3 * EL;    // EL [B,H,S,DK]
  u16* vT  = ws + 4 * EL;    // EL [B,H,DK,S]
  u16* ctx = ws + 5 * EL;    // EL [B,S,H*DK]
  u16* t1  = ws + 6 * EL;    // EL
  u16* hff = ws + 7 * EL;    // 4*EL [B,S,Dff]
  float* encF = (float*)(ws + 11 * EL);  // fp32 residual shadow (2*EL u16 units)
  float* decF = (float*)(ws + 13 * EL);  // fp32 residual shadow
  u16* wT  = ws + 15 * EL;   // 6*EL: 48 transposed bf16 512x512 matrices
  unsigned char* padE = (unsigned char*)(ws + 21 * EL);
  unsigned char* padD = padE + TOK;
  u16* wfAll = ws + 22 * EL; // 8*EL: [e_w1(4L), e_w2(4L), d_w1(4L), d_w2(4L)] bf16
  if (ws_size < 30 * EL * 2 + 2 * TOK) return;

  transpose_all<<<dim3(16, 16, 48), dim3(32, 8), 0, stream>>>(
      e_qkv_w, ds_qkv_w, dc_qkv_w, e_pw, ds_pw, dc_pw, wT);
  convert4<<<dim3(4096, 4), 256, 0, stream>>>(e_w1, e_w2, d_w1, d_w2, wfAll, (int)(4 * WFT));
  embed_k<<<dim3(TOK, 2), 256, 0, stream>>>(enc_in, dec_in, emb_w, emb_b, pos,
                                            enc, dec, encF, decF, padE, padD);

  // full MHA sublayer: x = LN(x + proj(flash_attn(q(qsrc), k(kvsrc), v(kvsrc))))
  auto attention = [&](const u16* qsrc, const u16* kvsrc, const u16* wq3, const float* b3,
                       const u16* pwT, const float* pb, const float* ln,
                       const unsigned char* pad, int mtype, u16* x, float* xF) {
    if (qsrc == kvsrc) {
      gemm_tile<64, 128><<<dim3(12, 64, 1), 256, 0, stream>>>(
          qsrc, wq3, b3, qb, 512, 512, 0, 512, 0, 0, 0, 4, 0, 0, nullptr, 0);
    } else {
      // merged cross Q (x<4: A=qsrc, cols 0..511) + KV (x>=4: A=kvsrc, cols 512..1535)
      gemm_tile<64, 128><<<dim3(12, 64, 1), 256, 0, stream>>>(
          qsrc, wq3, b3, qb, 512, 512, 0, 512, 0, 0, 0, 4, 0, 0, kvsrc, 4);
    }
    flash_attn<<<dim3(8, 64), 256, 0, stream>>>(qb, kb, vT, pad, ctx, mtype);
    gemm_tile<64, 64><<<dim3(8, 64, 1), 256, 0, stream>>>(
        ctx, pwT, pb, t1, 512, 512, 0, 512, 0, 512, 0, 0, 0, 0, nullptr, 0);
    add_ln<<<TOK / 4, 256, 0, stream>>>(xF, t1, ln, ln + 512, x);
  };

  auto ffn = [&](u16* x, float* xF, const u16* w1b, const float* b1, const u16* w2b,
                 const float* b2, const float* ln) {
    gemm_tile<128, 128><<<dim3(16, 32, 1), 256, 0, stream>>>(
        x, w1b, b1, hff, 512, 512, 0, 512, 0, 2048, 0, 0, 1, 0, nullptr, 0);
    gemm_tile<64, 64><<<dim3(8, 64, 1), 256, 0, stream>>>(
        hff, w2b, b2, t1, 2048, 2048, 0, 2048, 0, 512, 0, 0, 0, 0, nullptr, 0);
    add_ln<<<TOK / 4, 256, 0, stream>>>(xF, t1, ln, ln + 512, x);
  };

  for (int i = 0; i < NL; ++i) {
    attention(enc, enc, wT + (size_t)(i * 3) * MAT, e_qkv_b + i * 3 * 512,
              wT + (size_t)(36 + i) * MAT, e_pb + i * 512, e_ln1 + i * 1024, padE, 0, enc, encF);
    ffn(enc, encF, wfAll + (size_t)i * WFT, e_b1 + i * Dff,
        wfAll + 4 * WFT + (size_t)i * WFT, e_b2 + i * Dm, e_ln2 + i * 1024);
  }

  for (int i = 0; i < NL; ++i) {
    attention(dec, dec, wT + (size_t)(12 + i * 3) * MAT, ds_qkv_b + i * 3 * 512,
              wT + (size_t)(40 + i) * MAT, ds_pb + i * 512, d_ln1 + i * 1024, padD, 1, dec, decF);
    attention(dec, enc, wT + (size_t)(24 + i * 3) * MAT, dc_qkv_b + i * 3 * 512,
              wT + (size_t)(44 + i) * MAT, dc_pb + i * 512, d_ln2 + i * 1024, padE, 2, dec, decF);
    ffn(dec, decF, wfAll + 8 * WFT + (size_t)i * WFT, d_b1 + i * Dff,
        wfAll + 12 * WFT + (size_t)i * WFT, d_b2 + i * Dm, d_ln3 + i * 1024);
  }

  hipMemcpyAsync(d_out, decF, EL * sizeof(float), hipMemcpyDeviceToDevice, stream);
}

// Round 8
// 1418.227 us; speedup vs baseline: 1.0326x; 1.0326x over previous
//
#include <hip/hip_runtime.h>
#include <cstdint>
#include <cstddef>

typedef unsigned short u16;
typedef __bf16 bf16x8 __attribute__((ext_vector_type(8)));
typedef float f32x4 __attribute__((ext_vector_type(4)));

constexpr int Bz = 8, Sq = 512, Hh = 8, DKd = 64, Dm = 512, Dff = 2048, NL = 4;
constexpr int TOK = Bz * Sq;               // 4096 tokens
constexpr size_t MAT = (size_t)512 * 512;  // 262144 elems per 512x512 matrix
constexpr size_t EL  = (size_t)TOK * Dm;   // 2097152 elems per activation tensor
constexpr size_t WFT = (size_t)Dff * Dm;   // 1048576 elems per FFN matrix

__device__ __forceinline__ float bf2f(u16 u) {
  union { uint32_t i; float f; } v; v.i = (uint32_t)u << 16; return v.f;
}
__device__ __forceinline__ u16 f2bf(float f) {
  union { float f; uint32_t i; } v; v.f = f;
  uint32_t i = v.i;
  i += 0x7fffu + ((i >> 16) & 1u);   // round-to-nearest-even
  return (u16)(i >> 16);
}

// async global -> LDS, 16B per lane (global_load_lds_dwordx4)
__device__ __forceinline__ void gload16(const u16* g, u16* l) {
  __builtin_amdgcn_global_load_lds(
      (const __attribute__((address_space(1))) unsigned int*)g,
      (__attribute__((address_space(3))) unsigned int*)l, 16, 0, 0);
}

// ---------------------------------------------------------------------------
// Tiled NT GEMM: C[M,N] = A[M,K] @ Bt[N,K]^T (+bias fp32) (+relu)
// 256 threads = 4 waves (2x2); BK=64; global_load_lds staging, XOR chunk
// swizzle (c ^= row&7) -> ~2-way bank-safe ds_read_b128.
// cmode 0: plain write; 4: qkv split (Q scaled 0.125, Q->C [B,H,S,DK],
//          K->C+EL [B,H,S,DK], V->C+2EL transposed [B,H,DK,S]).
// A2/xsplit: blocks with blockIdx.x >= xsplit read A2 and write cols 512+.
// ---------------------------------------------------------------------------
template<int BM, int BN>
__global__ __launch_bounds__(256)
void gemm_tile(const u16* __restrict__ A, const u16* __restrict__ Bt,
               const float* __restrict__ bias, u16* __restrict__ C,
               int K, int lda, long long sA, int ldb, long long sB,
               int ldc, long long sC, int cmode, int relu, int colofs,
               const u16* A2, int xsplit)
{
  constexpr int HM = BM / 2, HN = BN / 2, MI = HM / 16, NI = HN / 16;
  __shared__ __align__(16) u16 As[BM * 64];
  __shared__ __align__(16) u16 Bs[BN * 64];
  const int bz = blockIdx.z;
  const u16* Abase = A;
  int colbase;
  if (A2 && (int)blockIdx.x >= xsplit) {
    Abase = A2;
    colbase = 512 + ((int)blockIdx.x - xsplit) * BN;
  } else {
    colbase = colofs + (int)blockIdx.x * BN;
  }
  const u16* Ab = Abase + (size_t)bz * (size_t)sA + (size_t)(blockIdx.y * BM) * lda;
  const u16* Bb = Bt + (size_t)bz * (size_t)sB + (size_t)colbase * ldb;
  const int tid  = threadIdx.x;
  const int lane = tid & 63;
  const int wid  = tid >> 6;
  const int l15  = lane & 15;
  const int quad = lane >> 4;
  const int wm   = wid >> 1, wn = wid & 1;

  f32x4 acc[MI][NI] = {};

  for (int k0 = 0; k0 < K; k0 += 64) {
#pragma unroll
    for (int i = 0; i < BM / 32; ++i) {          // A: BM rows x 64, 8 chunks/row
      const int s = tid + i * 256;
      const int row = s >> 3, c = (s & 7) ^ (row & 7);
      gload16(Ab + (size_t)row * lda + k0 + c * 8, As + s * 8);
    }
#pragma unroll
    for (int i = 0; i < BN / 32; ++i) {
      const int s = tid + i * 256;
      const int row = s >> 3, c = (s & 7) ^ (row & 7);
      gload16(Bb + (size_t)row * ldb + k0 + c * 8, Bs + s * 8);
    }
    __syncthreads();
#pragma unroll
    for (int kk = 0; kk < 2; ++kk) {
      bf16x8 af[MI], bfr[NI];
#pragma unroll
      for (int mi = 0; mi < MI; ++mi) {
        const int ra = wm * HM + mi * 16 + l15;
        af[mi] = *(const bf16x8*)(As + ra * 64 + (((kk * 4 + quad) ^ (ra & 7))) * 8);
      }
#pragma unroll
      for (int ni = 0; ni < NI; ++ni) {
        const int rb = wn * HN + ni * 16 + l15;
        bfr[ni] = *(const bf16x8*)(Bs + rb * 64 + (((kk * 4 + quad) ^ (rb & 7))) * 8);
      }
#pragma unroll
      for (int mi = 0; mi < MI; ++mi)
#pragma unroll
        for (int ni = 0; ni < NI; ++ni)
          acc[mi][ni] = __builtin_amdgcn_mfma_f32_16x16x32_bf16(af[mi], bfr[ni], acc[mi][ni], 0, 0, 0);
    }
    __syncthreads();
  }

  const int rblk = blockIdx.y * BM + wm * HM + quad * 4;
#pragma unroll
  for (int ni = 0; ni < NI; ++ni) {
    const int colx = colbase + wn * HN + ni * 16 + l15;
    const float bv = bias ? bias[colx] : 0.f;
#pragma unroll
    for (int mi = 0; mi < MI; ++mi) {
#pragma unroll
      for (int r = 0; r < 4; ++r) {
        float v = acc[mi][ni][r] + bv;
        if (relu) v = fmaxf(v, 0.f);
        const int grow = rblk + mi * 16 + r;
        size_t off;
        if (cmode == 0) {
          off = (size_t)bz * (size_t)sC + (size_t)grow * ldc + colx;
        } else {  // 4: qkv scatter; fold 1/sqrt(DK)=0.125 into Q
          const int sec = colx >> 9, n = colx & 511, h = n >> 6, d = n & 63;
          const int b = grow >> 9, s = grow & 511;
          if (sec == 0) v *= 0.125f;
          if (sec < 2) off = (size_t)sec * EL + (size_t)b * 262144 + (size_t)h * 32768 + (size_t)s * 64 + d;
          else         off = 2 * EL + (size_t)b * 262144 + (size_t)h * 32768 + (size_t)d * 512 + s;
        }
        C[off] = f2bf(v);
      }
    }
  }
}

// ---------------------------------------------------------------------------
// Fused attention: per block = (q-tile of 64 rows, one (b,h)).
// ctx[b,s,h*64+d] = softmax(mask(Q K^T)) V.  Q pre-scaled by 0.125.
// mtype 1 (causal): chunks beyond the q-tile's diagonal are fully masked ->
// skipped entirely (bit-exact: their P is identically 0).
// ---------------------------------------------------------------------------
__global__ __launch_bounds__(256)
void flash_attn(const u16* __restrict__ q, const u16* __restrict__ k,
                const u16* __restrict__ v, const unsigned char* __restrict__ pad,
                u16* __restrict__ ctx, int mtype)
{
  __shared__ __align__(16) u16 KVs[8192];      // 16 KB: K or V chunk (swizzled)
  __shared__ __align__(16) u16 Pw[4][2048];    // 4 KB per wave: P tile 16x128
  const int bh = blockIdx.y, b = bh >> 3, h = bh & 7;
  const int qt = blockIdx.x;
  const int tid = threadIdx.x, lane = tid & 63, wid = tid >> 6;
  const int l15 = lane & 15, quad = lane >> 4;
  const size_t bho = (size_t)bh * 32768;
  const int qrow = qt * 64 + wid * 16 + l15;       // A-operand row (this lane)
  const int qcd  = qt * 64 + wid * 16 + quad * 4;  // C-layout row base
  const int nkc  = (mtype == 1) ? (qt >> 1) + 1 : 4;  // live key chunks (uniform)

  unsigned char* Ps = (unsigned char*)&Pw[0][0];
  if (tid < 128) ((uchar4*)Ps)[tid] = ((const uchar4*)(pad + b * 512))[tid];

  bf16x8 aq0 = *(const bf16x8*)(q + bho + (size_t)qrow * 64 + quad * 8);
  bf16x8 aq1 = *(const bf16x8*)(q + bho + (size_t)qrow * 64 + 32 + quad * 8);

  f32x4 S[32];
#pragma unroll
  for (int kc = 0; kc < 4; ++kc) {
    if (kc < nkc) {
      __syncthreads();
#pragma unroll
      for (int i = 0; i < 4; ++i) {             // stage K chunk [128 keys][64]
        const int s = tid + i * 256;
        const int row = s >> 3, c = (s & 7) ^ (row & 7);
        gload16(k + bho + (size_t)(kc * 128 + row) * 64 + c * 8, KVs + s * 8);
      }
      __syncthreads();
#pragma unroll
      for (int t = 0; t < 8; ++t) {
        const int sw = l15 & 7;
        bf16x8 b0 = *(const bf16x8*)(KVs + (t * 16 + l15) * 64 + (quad ^ sw) * 8);
        bf16x8 b1 = *(const bf16x8*)(KVs + (t * 16 + l15) * 64 + ((4 + quad) ^ sw) * 8);
        f32x4 z = {0.f, 0.f, 0.f, 0.f};
        z = __builtin_amdgcn_mfma_f32_16x16x32_bf16(aq0, b0, z, 0, 0, 0);
        S[kc * 8 + t] = __builtin_amdgcn_mfma_f32_16x16x32_bf16(aq1, b1, z, 0, 0, 0);
      }
    }
  }

  unsigned pm = 0u;
#pragma unroll
  for (int t = 0; t < 32; ++t) pm |= (unsigned)(Ps[t * 16 + l15] != 0) << t;

  float inv[4];
#pragma unroll
  for (int r = 0; r < 4; ++r) {
    const int qg = qcd + r;
    float mx = -3.0e38f;
#pragma unroll
    for (int t = 0; t < 32; ++t) {
      if (t < nkc * 8) {
        const int col = t * 16 + l15;
        const bool m = ((pm >> t) & 1u) || (mtype == 1 && col > qg);
        const float val = m ? -1e9f : S[t][r];
        S[t][r] = val;
        mx = fmaxf(mx, val);
      }
    }
#pragma unroll
    for (int o = 8; o > 0; o >>= 1) mx = fmaxf(mx, __shfl_xor(mx, o));
    float sm = 0.f;
#pragma unroll
    for (int t = 0; t < 32; ++t) {
      if (t < nkc * 8) { const float e = __expf(S[t][r] - mx); S[t][r] = e; sm += e; }
    }
#pragma unroll
    for (int o = 8; o > 0; o >>= 1) sm += __shfl_xor(sm, o);
    inv[r] = 1.f / sm;
  }

  f32x4 O[4] = {};
  u16* myP = &Pw[wid][0];
#pragma unroll
  for (int kc = 0; kc < 4; ++kc) {
    if (kc < nkc) {
      __syncthreads();
#pragma unroll
      for (int i = 0; i < 4; ++i) {             // stage V chunk [64 dk][128 keys]
        const int s = tid + i * 256;
        const int row = s >> 4, c = (s & 15) ^ (row & 15);
        gload16(v + bho + (size_t)row * 512 + kc * 128 + c * 8, KVs + s * 8);
      }
#pragma unroll
      for (int t = 0; t < 8; ++t)
#pragma unroll
        for (int r = 0; r < 4; ++r) {
          const int rowq = quad * 4 + r;
          const int c = 2 * t + (l15 >> 3);
          myP[rowq * 128 + (c ^ rowq) * 8 + (l15 & 7)] = f2bf(S[kc * 8 + t][r] * inv[r]);
        }
      __syncthreads();
#pragma unroll
      for (int kk = 0; kk < 4; ++kk) {
        bf16x8 ap = *(const bf16x8*)(myP + l15 * 128 + ((kk * 4 + quad) ^ l15) * 8);
#pragma unroll
        for (int ni = 0; ni < 4; ++ni) {
          bf16x8 bv = *(const bf16x8*)(KVs + (ni * 16 + l15) * 128 + ((kk * 4 + quad) ^ l15) * 8);
          O[ni] = __builtin_amdgcn_mfma_f32_16x16x32_bf16(ap, bv, O[ni], 0, 0, 0);
        }
      }
    }
  }

  const int token = b * 512 + qcd;
#pragma unroll
  for (int ni = 0; ni < 4; ++ni)
#pragma unroll
    for (int r = 0; r < 4; ++r)
      ctx[(size_t)(token + r) * 512 + h * 64 + ni * 16 + l15] = f2bf(O[ni][r]);
}

// all 48 weight transposes in one dispatch (fp32 [K,N] -> bf16 [N,K])
__global__ __launch_bounds__(256)
void transpose_all(const float* __restrict__ s0, const float* __restrict__ s1,
                   const float* __restrict__ s2, const float* __restrict__ s3,
                   const float* __restrict__ s4, const float* __restrict__ s5,
                   u16* __restrict__ out)
{
  __shared__ float tile[32][33];
  const int z = blockIdx.z;
  const float* src; int zi;
  if      (z < 12) { src = s0; zi = z; }
  else if (z < 24) { src = s1; zi = z - 12; }
  else if (z < 36) { src = s2; zi = z - 24; }
  else if (z < 40) { src = s3; zi = z - 36; }
  else if (z < 44) { src = s4; zi = z - 40; }
  else             { src = s5; zi = z - 44; }
  const float* in = src + (size_t)zi * MAT;
  u16* o = out + (size_t)z * MAT;
  int x = blockIdx.x * 32 + threadIdx.x;
  int y = blockIdx.y * 32 + threadIdx.y;
#pragma unroll
  for (int i = 0; i < 32; i += 8)
    tile[threadIdx.y + i][threadIdx.x] = in[(size_t)(y + i) * 512 + x];
  __syncthreads();
  x = blockIdx.y * 32 + threadIdx.x;
  y = blockIdx.x * 32 + threadIdx.y;
#pragma unroll
  for (int i = 0; i < 32; i += 8)
    o[(size_t)(y + i) * 512 + x] = f2bf(tile[threadIdx.x][threadIdx.y + i]);
}

// convert 4 fp32 tensors (n elems each) -> bf16, packed consecutively in out
__global__ __launch_bounds__(256)
void convert4(const float* __restrict__ a, const float* __restrict__ b,
              const float* __restrict__ c, const float* __restrict__ d,
              u16* __restrict__ out, int n)
{
  const float* srcs[4] = { a, b, c, d };
  const float* src = srcs[blockIdx.y];
  u16* dst = out + (size_t)blockIdx.y * n;
  int i = (blockIdx.x * 256 + threadIdx.x) * 4;
  if (i < n) {
    float4 v = *(const float4*)(src + i);
    ushort4 u = { f2bf(v.x), f2bf(v.y), f2bf(v.z), f2bf(v.w) };
    *(ushort4*)(dst + i) = u;
  }
}

// embed enc+dec (blockIdx.y selects): out = concat(x, x@ew^T+eb)+pos (bf16);
// pad[b,s] = (sum_f x <= -9999). Wave-per-row, 4 rows/block, 8 cols/lane.
// Dot product kept in strict f=0..31 order (bit-matches prior rounds).
__global__ __launch_bounds__(256)
void embed_k(const float* __restrict__ xe, const float* __restrict__ xd,
             const float* __restrict__ ew, const float* __restrict__ eb,
             const float* __restrict__ pos,
             u16* __restrict__ oe, u16* __restrict__ od,
             unsigned char* __restrict__ pe, unsigned char* __restrict__ pd)
{
  const int which = blockIdx.y;
  const float* x = which ? xd : xe;
  u16* out = which ? od : oe;
  unsigned char* padv = which ? pd : pe;
  const int wid = threadIdx.x >> 6, lane = threadIdx.x & 63;
  const int rs = blockIdx.x * 4 + wid;       // b*512 + s
  const int s  = rs & 511;

  float xs[32];
#pragma unroll
  for (int j = 0; j < 8; ++j) {
    float4 v = *(const float4*)(x + (size_t)rs * 32 + j * 4);
    xs[j * 4 + 0] = v.x; xs[j * 4 + 1] = v.y; xs[j * 4 + 2] = v.z; xs[j * 4 + 3] = v.w;
  }
  if (lane == 0) {
    float sacc = 0.f;
#pragma unroll
    for (int f = 0; f < 32; ++f) sacc += xs[f];
    padv[rs] = (sacc <= -9999.f) ? 1 : 0;
  }
  const int c0 = lane * 8;
  float4 p0 = *(const float4*)(pos + (size_t)(s + 1) * 512 + c0);
  float4 p1 = *(const float4*)(pos + (size_t)(s + 1) * 512 + c0 + 4);
  const float pv[8] = { p0.x, p0.y, p0.z, p0.w, p1.x, p1.y, p1.z, p1.w };
  uint4 ow; u16* oh = (u16*)&ow;
#pragma unroll
  for (int j = 0; j < 8; ++j) {
    const int c = c0 + j;
    float v;
    if (c < 32) {
      v = xs[c];
    } else {
      const float* w = ew + (size_t)(c - 32) * 32;
      float wv[32];
#pragma unroll
      for (int q4 = 0; q4 < 8; ++q4) {
        float4 t = *(const float4*)(w + q4 * 4);
        wv[q4 * 4 + 0] = t.x; wv[q4 * 4 + 1] = t.y; wv[q4 * 4 + 2] = t.z; wv[q4 * 4 + 3] = t.w;
      }
      float acc = eb[c - 32];
#pragma unroll
      for (int f = 0; f < 32; ++f) acc += xs[f] * wv[f];
      v = acc;
    }
    oh[j] = f2bf(v + pv[j]);
  }
  *(uint4*)(out + (size_t)rs * 512 + c0) = ow;
}

// wave-per-row LN(x + y), torch-style (ddof=1, /(std+eps)). 4 rows/block.
// x,y,out bf16; g,b fp32. Safe for out == x (wave touches only its row).
__global__ __launch_bounds__(256)
void add_ln(const u16* __restrict__ x, const u16* __restrict__ y,
            const float* __restrict__ g, const float* __restrict__ bb,
            u16* __restrict__ out)
{
  const int row  = blockIdx.x * 4 + (threadIdx.x >> 6);
  const int lane = threadIdx.x & 63;
  const int c0 = lane * 8;
  const size_t base = (size_t)row * Dm + c0;

  uint4 xr = *(const uint4*)(x + base);
  uint4 yr = *(const uint4*)(y + base);
  const u16* xh = (const u16*)&xr;
  const u16* yh = (const u16*)&yr;
  float z[8];
  float s = 0.f;
#pragma unroll
  for (int j = 0; j < 8; ++j) { z[j] = bf2f(xh[j]) + bf2f(yh[j]); s += z[j]; }
#pragma unroll
  for (int off = 32; off > 0; off >>= 1) s += __shfl_xor(s, off);
  const float mean = s * (1.f / 512.f);
  float ss = 0.f;
#pragma unroll
  for (int j = 0; j < 8; ++j) { z[j] -= mean; ss += z[j] * z[j]; }
#pragma unroll
  for (int off = 32; off > 0; off >>= 1) ss += __shfl_xor(ss, off);
  const float stdv = sqrtf(ss * (1.f / 511.f));
  const float inv = 1.f / (stdv + 1e-6f);

  float4 g0 = *(const float4*)(g + c0),  g1 = *(const float4*)(g + c0 + 4);
  float4 b0 = *(const float4*)(bb + c0), b1 = *(const float4*)(bb + c0 + 4);
  float gv[8] = { g0.x, g0.y, g0.z, g0.w, g1.x, g1.y, g1.z, g1.w };
  float bv[8] = { b0.x, b0.y, b0.z, b0.w, b1.x, b1.y, b1.z, b1.w };
  uint4 ow;
  u16* oh = (u16*)&ow;
#pragma unroll
  for (int j = 0; j < 8; ++j) oh[j] = f2bf(gv[j] * z[j] * inv + bv[j]);
  *(uint4*)(out + base) = ow;
}

// bf16 -> fp32 final output, 8 per thread
__global__ __launch_bounds__(256)
void store_f32(const u16* __restrict__ in, float* __restrict__ out, int n)
{
  int i = (blockIdx.x * 256 + threadIdx.x) * 8;
  if (i < n) {
    uint4 raw = *(const uint4*)(in + i);
    const u16* h = (const u16*)&raw;
    float4 o0 = { bf2f(h[0]), bf2f(h[1]), bf2f(h[2]), bf2f(h[3]) };
    float4 o1 = { bf2f(h[4]), bf2f(h[5]), bf2f(h[6]), bf2f(h[7]) };
    *(float4*)(out + i) = o0;
    *(float4*)(out + i + 4) = o1;
  }
}

extern "C" void kernel_launch(void* const* d_in, const int* in_sizes, int n_in,
                              void* d_out, int out_size, void* d_ws, size_t ws_size,
                              hipStream_t stream)
{
  (void)in_sizes; (void)n_in; (void)out_size;
  const float* enc_in   = (const float*)d_in[0];
  const float* dec_in   = (const float*)d_in[1];
  const float* emb_w    = (const float*)d_in[2];
  const float* emb_b    = (const float*)d_in[3];
  const float* pos      = (const float*)d_in[4];
  const float* e_qkv_w  = (const float*)d_in[5];
  const float* e_qkv_b  = (const float*)d_in[6];
  const float* e_pw     = (const float*)d_in[7];
  const float* e_pb     = (const float*)d_in[8];
  const float* e_ln1    = (const float*)d_in[9];
  const float* e_w1     = (const float*)d_in[10];
  const float* e_b1     = (const float*)d_in[11];
  const float* e_w2     = (const float*)d_in[12];
  const float* e_b2     = (const float*)d_in[13];
  const float* e_ln2    = (const float*)d_in[14];
  const float* ds_qkv_w = (const float*)d_in[15];
  const float* ds_qkv_b = (const float*)d_in[16];
  const float* ds_pw    = (const float*)d_in[17];
  const float* ds_pb    = (const float*)d_in[18];
  const float* d_ln1    = (const float*)d_in[19];
  const float* dc_qkv_w = (const float*)d_in[20];
  const float* dc_qkv_b = (const float*)d_in[21];
  const float* dc_pw    = (const float*)d_in[22];
  const float* dc_pb    = (const float*)d_in[23];
  const float* d_ln2    = (const float*)d_in[24];
  const float* d_w1     = (const float*)d_in[25];
  const float* d_b1     = (const float*)d_in[26];
  const float* d_w2     = (const float*)d_in[27];
  const float* d_b2     = (const float*)d_in[28];
  const float* d_ln3    = (const float*)d_in[29];

  u16* ws  = (u16*)d_ws;
  u16* enc = ws;             // EL
  u16* dec = ws + EL;        // EL
  u16* qb  = ws + 2 * EL;    // EL [B,H,S,DK]  (K at +EL, V^T at +2EL)
  u16* kb  = ws + 3 * EL;    // EL [B,H,S,DK]
  u16* vT  = ws + 4 * EL;    // EL [B,H,DK,S]
  u16* ctx = ws + 5 * EL;    // EL [B,S,H*DK]
  u16* t1  = ws + 6 * EL;    // EL
  u16* hff = ws + 7 * EL;    // 4*EL [B,S,Dff]
  u16* wT  = ws + 15 * EL;   // 6*EL: 48 transposed bf16 512x512 matrices
  unsigned char* padE = (unsigned char*)(ws + 21 * EL);
  unsigned char* padD = padE + TOK;
  u16* wfAll = ws + 22 * EL; // 8*EL: [e_w1(4L), e_w2(4L), d_w1(4L), d_w2(4L)] bf16
  if (ws_size < 30 * EL * 2 + 2 * TOK) return;

  transpose_all<<<dim3(16, 16, 48), dim3(32, 8), 0, stream>>>(
      e_qkv_w, ds_qkv_w, dc_qkv_w, e_pw, ds_pw, dc_pw, wT);
  convert4<<<dim3(4096, 4), 256, 0, stream>>>(e_w1, e_w2, d_w1, d_w2, wfAll, (int)(4 * WFT));
  embed_k<<<dim3(TOK / 4, 2), 256, 0, stream>>>(enc_in, dec_in, emb_w, emb_b, pos,
                                                enc, dec, padE, padD);

  // full MHA sublayer: x = LN(x + proj(flash_attn(q(qsrc), k(kvsrc), v(kvsrc))))
  auto attention = [&](const u16* qsrc, const u16* kvsrc, const u16* wq3, const float* b3,
                       const u16* pwT, const float* pb, const float* ln,
                       const unsigned char* pad, int mtype, u16* x) {
    if (qsrc == kvsrc) {
      gemm_tile<64, 128><<<dim3(12, 64, 1), 256, 0, stream>>>(
          qsrc, wq3, b3, qb, 512, 512, 0, 512, 0, 0, 0, 4, 0, 0, nullptr, 0);
    } else {
      // merged cross Q (x<4: A=qsrc, cols 0..511) + KV (x>=4: A=kvsrc, cols 512..1535)
      gemm_tile<64, 128><<<dim3(12, 64, 1), 256, 0, stream>>>(
          qsrc, wq3, b3, qb, 512, 512, 0, 512, 0, 0, 0, 4, 0, 0, kvsrc, 4);
    }
    flash_attn<<<dim3(8, 64), 256, 0, stream>>>(qb, kb, vT, pad, ctx, mtype);
    gemm_tile<64, 64><<<dim3(8, 64, 1), 256, 0, stream>>>(
        ctx, pwT, pb, t1, 512, 512, 0, 512, 0, 512, 0, 0, 0, 0, nullptr, 0);
    add_ln<<<TOK / 4, 256, 0, stream>>>(x, t1, ln, ln + 512, x);
  };

  auto ffn = [&](u16* x, const u16* w1b, const float* b1, const u16* w2b,
                 const float* b2, const float* ln) {
    gemm_tile<64, 128><<<dim3(16, 64, 1), 256, 0, stream>>>(
        x, w1b, b1, hff, 512, 512, 0, 512, 0, 2048, 0, 0, 1, 0, nullptr, 0);
    gemm_tile<64, 64><<<dim3(8, 64, 1), 256, 0, stream>>>(
        hff, w2b, b2, t1, 2048, 2048, 0, 2048, 0, 512, 0, 0, 0, 0, nullptr, 0);
    add_ln<<<TOK / 4, 256, 0, stream>>>(x, t1, ln, ln + 512, x);
  };

  for (int i = 0; i < NL; ++i) {
    attention(enc, enc, wT + (size_t)(i * 3) * MAT, e_qkv_b + i * 3 * 512,
              wT + (size_t)(36 + i) * MAT, e_pb + i * 512, e_ln1 + i * 1024, padE, 0, enc);
    ffn(enc, wfAll + (size_t)i * WFT, e_b1 + i * Dff,
        wfAll + 4 * WFT + (size_t)i * WFT, e_b2 + i * Dm, e_ln2 + i * 1024);
  }

  for (int i = 0; i < NL; ++i) {
    attention(dec, dec, wT + (size_t)(12 + i * 3) * MAT, ds_qkv_b + i * 3 * 512,
              wT + (size_t)(40 + i) * MAT, ds_pb + i * 512, d_ln1 + i * 1024, padD, 1, dec);
    attention(dec, enc, wT + (size_t)(24 + i * 3) * MAT, dc_qkv_b + i * 3 * 512,
              wT + (size_t)(44 + i) * MAT, dc_pb + i * 512, d_ln2 + i * 1024, padE, 2, dec);
    ffn(dec, wfAll + 8 * WFT + (size_t)i * WFT, d_b1 + i * Dff,
        wfAll + 12 * WFT + (size_t)i * WFT, d_b2 + i * Dm, d_ln3 + i * 1024);
  }

  store_f32<<<(int)(EL / 8 / 256), 256, 0, stream>>>(dec, (float*)d_out, (int)EL);
}